// Round 1
// baseline (451.717 us; speedup 1.0000x reference)
//
#include <hip/hip_runtime.h>
#include <math.h>

// Problem dims (fixed by reference setup_inputs)
#define B_ 4
#define S_ 2048
#define D_ 1024
#define G_ 512
#define T_ 2047      // S-1 diff rows per batch
#define W_ 8
#define NROWS 8      // diff rows per block in main kernel

// ws layout (floats):
//   Gt      [D_][G_]      at 0          (524288)
//   r_gnorm [G_]          at 524288     (512)
//   magw    [B_*T_]       at 524800     (8188, padded to 8192)
//   blend   [B_*T_][D_]   at 532992     (8384512)
#define WS_GT    0
#define WS_RG    524288
#define WS_MW    524800
#define WS_BLEND 532992

// ---------------------------------------------------------------------------
// Kernel 0a: reciprocal guidance norms  rg[g] = 1/max(||guid[g]||, 1e-8)
// ---------------------------------------------------------------------------
__global__ __launch_bounds__(64) void gnorm_kernel(const float* __restrict__ guid,
                                                   float* __restrict__ rg) {
    int g = blockIdx.x;
    int lane = threadIdx.x;
    const float4* gp = (const float4*)(guid + (size_t)g * D_);
    float ss = 0.f;
#pragma unroll
    for (int j = 0; j < 4; ++j) {
        float4 v = gp[lane + j * 64];
        ss += v.x * v.x + v.y * v.y + v.z * v.z + v.w * v.w;
    }
#pragma unroll
    for (int m = 32; m >= 1; m >>= 1) ss += __shfl_xor(ss, m, 64);
    if (lane == 0) rg[g] = 1.0f / fmaxf(sqrtf(ss), 1e-8f);
}

// ---------------------------------------------------------------------------
// Kernel 0b: transpose guidance -> Gt[d][g] (coalesced dots-phase loads)
// grid (D_/32, G_/32), block (32, 8)
// ---------------------------------------------------------------------------
__global__ __launch_bounds__(256) void transpose_kernel(const float* __restrict__ guid,
                                                        float* __restrict__ Gt) {
    __shared__ float tile[32][33];
    int tx = threadIdx.x;  // 0..31
    int ty = threadIdx.y;  // 0..7
    int d0 = blockIdx.x * 32;
    int g0 = blockIdx.y * 32;
#pragma unroll
    for (int i = 0; i < 4; ++i) {
        int gl = ty + i * 8;
        tile[gl][tx] = guid[(size_t)(g0 + gl) * D_ + d0 + tx];
    }
    __syncthreads();
#pragma unroll
    for (int i = 0; i < 4; ++i) {
        int dl = ty + i * 8;
        Gt[(size_t)(d0 + dl) * G_ + g0 + tx] = tile[tx][dl];
    }
}

// ---------------------------------------------------------------------------
// Kernel A: per (b, t-tile of 8 rows): diff -> normalize -> dots vs all 512 g
//           -> softmax -> influence -> blend. Stores blend row + magw.
// grid B_*256 blocks, 256 threads.
// LDS: nrm 32KB + sm 16KB -> 3 blocks/CU.
// ---------------------------------------------------------------------------
__global__ __launch_bounds__(256) void main_kernel(const float* __restrict__ emb,
                                                   const float* __restrict__ guid,
                                                   const float* __restrict__ Gt,
                                                   const float* __restrict__ rg,
                                                   float* __restrict__ magw,
                                                   float* __restrict__ blend) {
    __shared__ float nrm[NROWS][D_];   // normalized diffs
    __shared__ float sm[NROWS][G_];    // sims -> exp weights (unnormalized)
    __shared__ float rsums[NROWS];     // 1/sum(exp)

    int tid = threadIdx.x;
    int b = blockIdx.x >> 8;            // 256 blocks per batch
    int t0 = (blockIdx.x & 255) * NROWS;

    // ---- Phase 1: diffs -> LDS (each thread loads float4 per row) ----
#pragma unroll
    for (int r = 0; r < NROWS; ++r) {
        int t = t0 + r;
        float4 dv;
        if (t < T_) {
            const float4* p = (const float4*)(emb + ((size_t)b * S_ + t) * D_);
            float4 a = p[tid];            // emb[b][t]
            float4 c = p[tid + D_ / 4];   // emb[b][t+1] (next row, contiguous)
            dv = make_float4(c.x - a.x, c.y - a.y, c.z - a.z, c.w - a.w);
        } else {
            dv = make_float4(0.f, 0.f, 0.f, 0.f);
        }
        *(float4*)&nrm[r][tid * 4] = dv;
    }
    __syncthreads();

    // ---- Phase 2: row magnitudes + in-place normalize (32-lane teams) ----
    {
        int r = tid >> 5, lane = tid & 31;
        float ss = 0.f;
#pragma unroll
        for (int j = 0; j < 8; ++j) {
            float4 v = *(const float4*)&nrm[r][(lane + j * 32) * 4];
            ss += v.x * v.x + v.y * v.y + v.z * v.z + v.w * v.w;
        }
#pragma unroll
        for (int m = 16; m >= 1; m >>= 1) ss += __shfl_xor(ss, m, 32);
        float mag = sqrtf(ss);
        float rmag = (mag > 1e-6f) ? (1.0f / mag) : 0.0f;
        int t = t0 + r;
        if (lane == 0 && t < T_) magw[(size_t)b * T_ + t] = tanhf(2.0f * mag);
#pragma unroll
        for (int j = 0; j < 8; ++j) {
            float4 v = *(float4*)&nrm[r][(lane + j * 32) * 4];
            v.x *= rmag; v.y *= rmag; v.z *= rmag; v.w *= rmag;
            *(float4*)&nrm[r][(lane + j * 32) * 4] = v;
        }
    }
    __syncthreads();

    // ---- Phase 3: dots. thread owns g = 2*tid, 2*tid+1 via Gt float2 ----
    {
        float acc0[NROWS], acc1[NROWS];
#pragma unroll
        for (int r = 0; r < NROWS; ++r) { acc0[r] = 0.f; acc1[r] = 0.f; }
        const float2* Gt2 = (const float2*)Gt;  // [D_][G_/2]
        for (int d = 0; d < D_; d += 4) {
            float2 gv0 = Gt2[(size_t)(d + 0) * (G_ / 2) + tid];
            float2 gv1 = Gt2[(size_t)(d + 1) * (G_ / 2) + tid];
            float2 gv2 = Gt2[(size_t)(d + 2) * (G_ / 2) + tid];
            float2 gv3 = Gt2[(size_t)(d + 3) * (G_ / 2) + tid];
#pragma unroll
            for (int r = 0; r < NROWS; ++r) {
                float4 n4 = *(const float4*)&nrm[r][d];  // wave-broadcast LDS read
                acc0[r] += n4.x * gv0.x + n4.y * gv1.x + n4.z * gv2.x + n4.w * gv3.x;
                acc1[r] += n4.x * gv0.y + n4.y * gv1.y + n4.z * gv2.y + n4.w * gv3.y;
            }
        }
        float rgv0 = rg[2 * tid], rgv1 = rg[2 * tid + 1];
#pragma unroll
        for (int r = 0; r < NROWS; ++r) {
            *(float2*)&sm[r][2 * tid] = make_float2(acc0[r] * rgv0, acc1[r] * rgv1);
        }
    }
    __syncthreads();

    // ---- Phase 4: per-row softmax over 512 g (logits = 2*sims) ----
    {
        int r = tid >> 5, lane = tid & 31;
        float mx = -1e30f;
#pragma unroll
        for (int j = 0; j < 8; ++j) {
            float2 v = *(const float2*)&sm[r][(lane + j * 32) * 2];
            mx = fmaxf(mx, fmaxf(v.x, v.y));
        }
#pragma unroll
        for (int m = 16; m >= 1; m >>= 1) mx = fmaxf(mx, __shfl_xor(mx, m, 32));
        float sum = 0.f;
#pragma unroll
        for (int j = 0; j < 8; ++j) {
            float2 v = *(float2*)&sm[r][(lane + j * 32) * 2];
            v.x = __expf(2.0f * (v.x - mx));
            v.y = __expf(2.0f * (v.y - mx));
            sum += v.x + v.y;
            *(float2*)&sm[r][(lane + j * 32) * 2] = v;
        }
#pragma unroll
        for (int m = 16; m >= 1; m >>= 1) sum += __shfl_xor(sum, m, 32);
        if (lane == 0) rsums[r] = 1.0f / sum;
    }
    __syncthreads();

    // ---- Phase 5: influence (thread owns 4 d's) + blend + store ----
    {
        float4 facc[NROWS];
#pragma unroll
        for (int r = 0; r < NROWS; ++r) facc[r] = make_float4(0.f, 0.f, 0.f, 0.f);
        const float4* gg = (const float4*)guid;  // [G_][D_/4], coalesced over d
        for (int g = 0; g < G_; g += 2) {
            float4 gv0 = gg[(size_t)g * (D_ / 4) + tid];
            float4 gv1 = gg[(size_t)(g + 1) * (D_ / 4) + tid];
#pragma unroll
            for (int r = 0; r < NROWS; ++r) {
                float2 w = *(const float2*)&sm[r][g];  // wave-broadcast
                facc[r].x += w.x * gv0.x + w.y * gv1.x;
                facc[r].y += w.x * gv0.y + w.y * gv1.y;
                facc[r].z += w.x * gv0.z + w.y * gv1.z;
                facc[r].w += w.x * gv0.w + w.y * gv1.w;
            }
        }
#pragma unroll
        for (int r = 0; r < NROWS; ++r) {
            int t = t0 + r;
            if (t < T_) {
                float4 n4 = *(const float4*)&nrm[r][tid * 4];
                float s04 = 0.4f * rsums[r];
                float4 o;
                o.x = 0.6f * n4.x + s04 * facc[r].x;
                o.y = 0.6f * n4.y + s04 * facc[r].y;
                o.z = 0.6f * n4.z + s04 * facc[r].z;
                o.w = 0.6f * n4.w + s04 * facc[r].w;
                *(float4*)&blend[((size_t)b * T_ + t) * D_ + tid * 4] = o;
            }
        }
    }
}

// ---------------------------------------------------------------------------
// Kernel B: 8-tap windowed combine over blend rows.
// out[b,s,:] = sum_{j<w} lin(j,w)*magw[b,s-w+j]*blend[b,s-w+j,:] / max(wsum,1e-8)
// grid B_*S_ blocks, 256 threads (float4 per thread).
// ---------------------------------------------------------------------------
__global__ __launch_bounds__(256) void combine_kernel(const float* __restrict__ magw,
                                                      const float* __restrict__ blend,
                                                      float* __restrict__ out) {
    int blk = blockIdx.x;
    int b = blk >> 11;          // S_ = 2048
    int s = blk & (S_ - 1);
    int tid = threadIdx.x;
    float4 acc = make_float4(0.f, 0.f, 0.f, 0.f);
    float wsum = 0.f;
    int w = min(s, W_);
    float rw = (w > 1) ? 0.9f / (float)(w - 1) : 0.0f;
    for (int j = 0; j < w; ++j) {
        int t = s - w + j;
        float lin = 0.1f + rw * (float)j;
        float wt = lin * magw[(size_t)b * T_ + t];
        const float4* bp = (const float4*)(blend + ((size_t)b * T_ + t) * D_);
        float4 v = bp[tid];
        acc.x += wt * v.x; acc.y += wt * v.y; acc.z += wt * v.z; acc.w += wt * v.w;
        wsum += wt;
    }
    float rws = 1.0f / fmaxf(wsum, 1e-8f);
    float4 o = make_float4(acc.x * rws, acc.y * rws, acc.z * rws, acc.w * rws);
    *(float4*)&out[((size_t)b * S_ + s) * D_ + tid * 4] = o;
}

// ---------------------------------------------------------------------------
extern "C" void kernel_launch(void* const* d_in, const int* in_sizes, int n_in,
                              void* d_out, int out_size, void* d_ws, size_t ws_size,
                              hipStream_t stream) {
    const float* emb  = (const float*)d_in[0];   // (4, 2048, 1024) fp32
    const float* guid = (const float*)d_in[1];   // (512, 1024) fp32
    float* out = (float*)d_out;                  // (4, 2048, 1024) fp32
    float* ws  = (float*)d_ws;

    float* Gt    = ws + WS_GT;
    float* rg    = ws + WS_RG;
    float* magw  = ws + WS_MW;
    float* blend = ws + WS_BLEND;

    gnorm_kernel<<<G_, 64, 0, stream>>>(guid, rg);
    transpose_kernel<<<dim3(D_ / 32, G_ / 32), dim3(32, 8), 0, stream>>>(guid, Gt);
    main_kernel<<<B_ * 256, 256, 0, stream>>>(emb, guid, Gt, rg, magw, blend);
    combine_kernel<<<B_ * S_, 256, 0, stream>>>(magw, blend, out);
}

// Round 2
// 244.861 us; speedup vs baseline: 1.8448x; 1.8448x over previous
//
#include <hip/hip_runtime.h>
#include <math.h>

// Dims fixed by reference setup_inputs
#define B_ 4
#define S_ 2048
#define D_ 1024
#define G_ 512
#define T_ 2047          // diff rows per batch
#define R_ 8188          // B_*T_ valid rows
#define RPAD 8192        // padded to multiple of 16 for MFMA M-tiles

typedef __attribute__((ext_vector_type(8))) short short8;
typedef __attribute__((ext_vector_type(4))) float f32x4;

// ws byte offsets
#define WSOFF_RG2  0u           // 512 f  (2*1/max(||g||,1e-8))
#define WSOFF_MAGW 2048u        // 8192 f
#define WSOFF_BP1  34816u       // Bpack1: [128][512] short8  (1 MB)  B-frag for gemm1
#define WSOFF_BP2  1083392u     // Bpack2: [64][1024] short8  (1 MB)  B-frag for gemm2
#define WSOFF_WN   2131968u     // wnorm:  [8192][512] bf16   (8 MB)
#define WSOFF_NH   10520576u    // normh:  [8192][1024] bf16  (16 MB)
#define WSOFF_BL   27297792u    // blend:  [8192][1024] f32   (32 MB) normed then blended in place

__device__ inline short to_bf16(float f) {
    union { float f; unsigned u; } v; v.f = f;
    unsigned r = v.u + 0x7fffu + ((v.u >> 16) & 1u);
    return (short)(r >> 16);
}

// ---------------------------------------------------------------------------
// prep1: per guidance row g: rg2[g] = 2/max(||g||,1e-8); pack Bpack1 for gemm1.
// Bpack1[k/8][g][k&7] = bf16(guid[g][k])  -> lane's B-frag is 16B contiguous.
// grid 512 x 64
// ---------------------------------------------------------------------------
__global__ __launch_bounds__(64) void prep1_kernel(const float* __restrict__ guid,
                                                   float* __restrict__ rg2,
                                                   short8* __restrict__ Bp1) {
    int g = blockIdx.x, lane = threadIdx.x;
    const float4* gp = (const float4*)(guid + (size_t)g * D_);
    float ss = 0.f;
#pragma unroll
    for (int i = 0; i < 4; ++i) {
        float4 v = gp[lane + 64 * i];
        ss += v.x * v.x + v.y * v.y + v.z * v.z + v.w * v.w;
    }
#pragma unroll
    for (int m = 32; m >= 1; m >>= 1) ss += __shfl_xor(ss, m, 64);
    if (lane == 0) rg2[g] = 2.0f / fmaxf(sqrtf(ss), 1e-8f);
#pragma unroll
    for (int h = 0; h < 2; ++h) {
        int kg = lane + 64 * h;
        const float* src = guid + (size_t)g * D_ + kg * 8;
        short8 v;
#pragma unroll
        for (int j = 0; j < 8; ++j) v[j] = to_bf16(src[j]);
        Bp1[(size_t)kg * G_ + g] = v;
    }
}

// ---------------------------------------------------------------------------
// prep2: pack Bpack2 for gemm2. Bpack2[g/8][d][g&7] = bf16(guid[g][d]).
// grid 64 x 256
// ---------------------------------------------------------------------------
__global__ __launch_bounds__(256) void prep2_kernel(const float* __restrict__ guid,
                                                    short8* __restrict__ Bp2) {
    int gg = blockIdx.x, tid = threadIdx.x;
#pragma unroll
    for (int dd = 0; dd < 4; ++dd) {
        int d = tid + 256 * dd;
        short8 v;
#pragma unroll
        for (int j = 0; j < 8; ++j) v[j] = to_bf16(guid[(size_t)(gg * 8 + j) * D_ + d]);
        Bp2[(size_t)gg * D_ + d] = v;
    }
}

// ---------------------------------------------------------------------------
// diff_kernel: per row r=b*T_+t: normed = (emb[b][t+1]-emb[b][t])/||.||
//   -> blend (fp32, overwritten later), normh (bf16 A-layout), magw=tanh(2mag)
// grid 2048 x 256 (4 rows/block, one wave per row)
// ---------------------------------------------------------------------------
__global__ __launch_bounds__(256) void diff_kernel(const float* __restrict__ emb,
                                                   float* __restrict__ magw,
                                                   short* __restrict__ normh,
                                                   float* __restrict__ blendf) {
    int tid = threadIdx.x;
    int r = blockIdx.x * 4 + (tid >> 6);
    int lane = tid & 63;
    short8* nh8 = (short8*)(normh + (size_t)r * D_) + lane * 2;
    if (r >= R_) {   // pad rows: zero bf16 so gemm1 sees clean zeros
        short8 z = (short8)0;
        nh8[0] = z; nh8[1] = z;
        return;
    }
    int b = r / T_;
    int t = r - b * T_;
    const float4* p = (const float4*)(emb + ((size_t)b * S_ + t) * D_);
    float4 dv[4];
    float ss = 0.f;
#pragma unroll
    for (int i = 0; i < 4; ++i) {
        float4 x0 = p[lane * 4 + i];
        float4 x1 = p[lane * 4 + i + 256];   // next row, contiguous
        dv[i] = make_float4(x1.x - x0.x, x1.y - x0.y, x1.z - x0.z, x1.w - x0.w);
        ss += dv[i].x * dv[i].x + dv[i].y * dv[i].y + dv[i].z * dv[i].z + dv[i].w * dv[i].w;
    }
#pragma unroll
    for (int m = 32; m >= 1; m >>= 1) ss += __shfl_xor(ss, m, 64);
    float mag = sqrtf(ss);
    float rmag = (mag > 1e-6f) ? (1.0f / mag) : 0.0f;
    if (lane == 0) magw[r] = tanhf(2.0f * mag);
    float4* bf4 = (float4*)(blendf + (size_t)r * D_) + lane * 4;
    short8 h[2];
#pragma unroll
    for (int i = 0; i < 4; ++i) {
        float4 n = make_float4(dv[i].x * rmag, dv[i].y * rmag, dv[i].z * rmag, dv[i].w * rmag);
        bf4[i] = n;
        h[i >> 1][(i & 1) * 4 + 0] = to_bf16(n.x);
        h[i >> 1][(i & 1) * 4 + 1] = to_bf16(n.y);
        h[i >> 1][(i & 1) * 4 + 2] = to_bf16(n.z);
        h[i >> 1][(i & 1) * 4 + 3] = to_bf16(n.w);
    }
    nh8[0] = h[0]; nh8[1] = h[1];
}

// ---------------------------------------------------------------------------
// gemm1: sims = normh x Gt (MFMA), fused softmax, write normalized weights bf16.
// grid 512 (M-tiles of 16 rows) x 256 (4 waves; wave w owns g in [128w,128w+128))
// ---------------------------------------------------------------------------
__global__ __launch_bounds__(256) void gemm1_kernel(const short* __restrict__ normh,
                                                    const short8* __restrict__ Bp1,
                                                    const float* __restrict__ rg2,
                                                    short* __restrict__ wnorm) {
    __shared__ float smf[16][516];        // logits (pad 516: 2-way LDS alias, free)
    __shared__ float redmx[16], redrs[16];
    int tid = threadIdx.x;
    int wave = tid >> 6, lane = tid & 63;
    int l15 = lane & 15, quad = lane >> 4;
    int m0 = blockIdx.x * 16;
    int g0 = wave * 128;
    f32x4 acc[8];
#pragma unroll
    for (int nt = 0; nt < 8; ++nt) acc[nt] = (f32x4)0.f;
    // A-frag: normh[m0+l15][32*ks + quad*8 + j], row-major == native A layout
    const short8* A8 = (const short8*)(normh + (size_t)(m0 + l15) * D_) + quad;
    const short8* Bb = Bp1 + (size_t)quad * G_ + g0 + l15;
    for (int ks = 0; ks < 32; ++ks) {
        short8 a = A8[ks * 4];
        const short8* Bk = Bb + (size_t)ks * 4 * G_;
#pragma unroll
        for (int nt = 0; nt < 8; ++nt)
            acc[nt] = __builtin_amdgcn_mfma_f32_16x16x32_bf16(a, Bk[nt * 16], acc[nt], 0, 0, 0);
    }
    // C layout: row=quad*4+r, col=g0+nt*16+l15. logits = dot * (2/||g||)
#pragma unroll
    for (int nt = 0; nt < 8; ++nt) {
        int g = g0 + nt * 16 + l15;
        float rgv = rg2[g];
#pragma unroll
        for (int r = 0; r < 4; ++r) smf[quad * 4 + r][g] = acc[nt][r] * rgv;
    }
    __syncthreads();
    {   // row softmax reduce: 16 teams of 16 lanes
        int row = tid >> 4, t16 = tid & 15;
        float mx = -1e30f;
        for (int i = 0; i < 32; ++i) mx = fmaxf(mx, smf[row][t16 + 16 * i]);
#pragma unroll
        for (int m = 8; m >= 1; m >>= 1) mx = fmaxf(mx, __shfl_xor(mx, m, 16));
        float sum = 0.f;
        for (int i = 0; i < 32; ++i) sum += __expf(smf[row][t16 + 16 * i] - mx);
#pragma unroll
        for (int m = 8; m >= 1; m >>= 1) sum += __shfl_xor(sum, m, 16);
        if (t16 == 0) { redmx[row] = mx; redrs[row] = 1.0f / sum; }
    }
    __syncthreads();
    // coalesced bf16 write of normalized weights (row-major == gemm2 A layout)
#pragma unroll
    for (int i = 0; i < 32; ++i) {
        int idx = tid + 256 * i;
        int row = idx >> 9, g = idx & 511;
        float wv = __expf(smf[row][g] - redmx[row]) * redrs[row];
        wnorm[(size_t)(m0 + row) * G_ + g] = to_bf16(wv);
    }
}

// ---------------------------------------------------------------------------
// gemm2: infl = wnorm x guid (MFMA); blend = 0.6*normed + 0.4*infl, in place.
// grid 512 x 256 (wave w owns d in [256w, 256w+256))
// ---------------------------------------------------------------------------
__global__ __launch_bounds__(256) void gemm2_kernel(const short* __restrict__ wnorm,
                                                    const short8* __restrict__ Bp2,
                                                    float* __restrict__ blend) {
    int tid = threadIdx.x;
    int wave = tid >> 6, lane = tid & 63;
    int l15 = lane & 15, quad = lane >> 4;
    int m0 = blockIdx.x * 16;
    int d0 = wave * 256;
    f32x4 acc[16];
#pragma unroll
    for (int nt = 0; nt < 16; ++nt) acc[nt] = (f32x4)0.f;
    const short8* A8 = (const short8*)(wnorm + (size_t)(m0 + l15) * G_) + quad;
    const short8* Bb = Bp2 + (size_t)quad * D_ + d0 + l15;
    for (int ks = 0; ks < 16; ++ks) {
        short8 a = A8[ks * 4];
        const short8* Bk = Bb + (size_t)ks * 4 * D_;
#pragma unroll
        for (int nt = 0; nt < 16; ++nt)
            acc[nt] = __builtin_amdgcn_mfma_f32_16x16x32_bf16(a, Bk[nt * 16], acc[nt], 0, 0, 0);
    }
#pragma unroll
    for (int nt = 0; nt < 16; ++nt) {
        int d = d0 + nt * 16 + l15;
#pragma unroll
        for (int r = 0; r < 4; ++r) {
            int row = m0 + quad * 4 + r;
            if (row < R_) {
                size_t off = (size_t)row * D_ + d;
                blend[off] = 0.6f * blend[off] + 0.4f * acc[nt][r];
            }
        }
    }
}

// ---------------------------------------------------------------------------
// combine: register ring-buffer 8-tap window; block = 16 consecutive s, one b.
// slot(t) = (t - s0) & 7 (s0 % 8 == 0 -> all slots compile-time)
// grid 512 x 256
// ---------------------------------------------------------------------------
__global__ __launch_bounds__(256) void combine_kernel(const float* __restrict__ magw,
                                                      const float* __restrict__ blend,
                                                      float* __restrict__ out) {
    int blk = blockIdx.x;
    int b = blk >> 7;                 // S_/16 = 128 chunks per batch
    int s0 = (blk & 127) * 16;
    int tid = threadIdx.x;
    const float4* bl4 = (const float4*)blend;
    float4* out4 = (float4*)out;
    size_t rbase = (size_t)b * T_;
    float4 ring[8]; float mring[8];
#pragma unroll
    for (int a2 = 0; a2 < 8; ++a2) { ring[a2] = make_float4(0.f, 0.f, 0.f, 0.f); mring[a2] = 0.f; }
#pragma unroll
    for (int a2 = 0; a2 < 7; ++a2) {  // preload t = s0-8 .. s0-2 into slots 0..6
        int t = s0 - 8 + a2;
        if (t >= 0) {
            ring[a2] = bl4[(rbase + t) * 256 + tid];
            mring[a2] = magw[rbase + t];
        }
    }
    if (s0 != 0) {
#pragma unroll
        for (int i = 0; i < 16; ++i) {
            int t = s0 + i - 1;
            ring[(i + 7) & 7] = bl4[(rbase + t) * 256 + tid];
            mring[(i + 7) & 7] = magw[rbase + t];
            float4 acc = make_float4(0.f, 0.f, 0.f, 0.f); float wsum = 0.f;
#pragma unroll
            for (int a = 1; a <= 8; ++a) {     // w = 8: lin = 0.1 + 0.9*(8-a)/7
                int slot = (i - a) & 7;
                float lin = 0.1f + (0.9f / 7.0f) * (float)(8 - a);
                float wt = lin * mring[slot];
                float4 v = ring[slot];
                acc.x += wt * v.x; acc.y += wt * v.y; acc.z += wt * v.z; acc.w += wt * v.w;
                wsum += wt;
            }
            float rws = 1.0f / fmaxf(wsum, 1e-8f);
            out4[((size_t)b * S_ + s0 + i) * 256 + tid] =
                make_float4(acc.x * rws, acc.y * rws, acc.z * rws, acc.w * rws);
        }
    } else {
#pragma unroll
        for (int i = 0; i < 16; ++i) {
            if (i >= 1) {
                int t = i - 1;
                ring[(i + 7) & 7] = bl4[(rbase + t) * 256 + tid];
                mring[(i + 7) & 7] = magw[rbase + t];
            }
            int w = (i < 8) ? i : 8;
            float rw = (w > 1) ? 0.9f / (float)(w - 1) : 0.0f;
            float4 acc = make_float4(0.f, 0.f, 0.f, 0.f); float wsum = 0.f;
            for (int a = 1; a <= w; ++a) {
                int slot = (i - a) & 7;
                float lin = 0.1f + rw * (float)(w - a);
                float wt = lin * mring[slot];
                float4 v = ring[slot];
                acc.x += wt * v.x; acc.y += wt * v.y; acc.z += wt * v.z; acc.w += wt * v.w;
                wsum += wt;
            }
            float rws = 1.0f / fmaxf(wsum, 1e-8f);
            out4[((size_t)b * S_ + i) * 256 + tid] =
                make_float4(acc.x * rws, acc.y * rws, acc.z * rws, acc.w * rws);
        }
    }
}

// ---------------------------------------------------------------------------
extern "C" void kernel_launch(void* const* d_in, const int* in_sizes, int n_in,
                              void* d_out, int out_size, void* d_ws, size_t ws_size,
                              hipStream_t stream) {
    const float* emb  = (const float*)d_in[0];
    const float* guid = (const float*)d_in[1];
    float* out = (float*)d_out;
    char* ws = (char*)d_ws;

    float*  rg2   = (float*)(ws + WSOFF_RG2);
    float*  magw  = (float*)(ws + WSOFF_MAGW);
    short8* Bp1   = (short8*)(ws + WSOFF_BP1);
    short8* Bp2   = (short8*)(ws + WSOFF_BP2);
    short*  wnorm = (short*)(ws + WSOFF_WN);
    short*  normh = (short*)(ws + WSOFF_NH);
    float*  blend = (float*)(ws + WSOFF_BL);

    prep1_kernel<<<G_, 64, 0, stream>>>(guid, rg2, Bp1);
    prep2_kernel<<<G_ / 8, 256, 0, stream>>>(guid, Bp2);
    diff_kernel<<<RPAD / 4, 256, 0, stream>>>(emb, magw, normh, blend);
    gemm1_kernel<<<RPAD / 16, 256, 0, stream>>>(normh, Bp1, rg2, wnorm);
    gemm2_kernel<<<RPAD / 16, 256, 0, stream>>>(wnorm, Bp2, blend);
    combine_kernel<<<B_ * (S_ / 16), 256, 0, stream>>>(magw, blend, out);
}

// Round 3
// 141.026 us; speedup vs baseline: 3.2031x; 1.7363x over previous
//
#include <hip/hip_runtime.h>
#include <math.h>

// Dims fixed by reference setup_inputs
#define B_ 4
#define S_ 2048
#define D_ 1024
#define G_ 512
#define T_ 2047          // diff rows per batch
#define R_ 8188          // B_*T_ valid rows
#define RPAD 8192
#define MT 16            // diff rows per fused block

typedef __attribute__((ext_vector_type(8))) short short8;
typedef __attribute__((ext_vector_type(4))) short s16x4;
typedef __attribute__((ext_vector_type(4))) float f32x4;

// ws byte offsets
#define WSOFF_RG2  0u           // 512 f: 2/max(||g||,1e-8)
#define WSOFF_MAGW 2048u        // 8192 f
#define WSOFF_BP1  34816u       // Bpack1 [128][512] short8 (1 MB)
#define WSOFF_BP2  1083392u     // Bpack2 [64][1024] short8 (1 MB)
#define WSOFF_BL   2131968u     // blend  [8192][1024] f32  (32 MB)

__device__ inline short to_bf16(float f) {
    union { float f; unsigned u; } v; v.f = f;
    unsigned r = v.u + 0x7fffu + ((v.u >> 16) & 1u);
    return (short)(r >> 16);
}
__device__ inline float from_bf16(short h) {
    union { unsigned u; float f; } v;
    v.u = ((unsigned)(unsigned short)h) << 16;
    return v.f;
}

// ---------------------------------------------------------------------------
// prep1: rg2[g] = 2/max(||guid[g]||,1e-8); Bpack1[k/8][g][k&7] = bf16(guid[g][k])
// ---------------------------------------------------------------------------
__global__ __launch_bounds__(64) void prep1_kernel(const float* __restrict__ guid,
                                                   float* __restrict__ rg2,
                                                   short8* __restrict__ Bp1) {
    int g = blockIdx.x, lane = threadIdx.x;
    const float4* gp = (const float4*)(guid + (size_t)g * D_);
    float ss = 0.f;
#pragma unroll
    for (int i = 0; i < 4; ++i) {
        float4 v = gp[lane + 64 * i];
        ss += v.x * v.x + v.y * v.y + v.z * v.z + v.w * v.w;
    }
#pragma unroll
    for (int m = 32; m >= 1; m >>= 1) ss += __shfl_xor(ss, m, 64);
    if (lane == 0) rg2[g] = 2.0f / fmaxf(sqrtf(ss), 1e-8f);
#pragma unroll
    for (int h = 0; h < 2; ++h) {
        int kg = lane + 64 * h;
        const float* src = guid + (size_t)g * D_ + kg * 8;
        short8 v;
#pragma unroll
        for (int j = 0; j < 8; ++j) v[j] = to_bf16(src[j]);
        Bp1[(size_t)kg * G_ + g] = v;
    }
}

// ---------------------------------------------------------------------------
// prep2: Bpack2[g/8][d][g&7] = bf16(guid[g][d])
// ---------------------------------------------------------------------------
__global__ __launch_bounds__(256) void prep2_kernel(const float* __restrict__ guid,
                                                    short8* __restrict__ Bp2) {
    int gg = blockIdx.x, tid = threadIdx.x;
#pragma unroll
    for (int dd = 0; dd < 4; ++dd) {
        int d = tid + 256 * dd;
        short8 v;
#pragma unroll
        for (int j = 0; j < 8; ++j) v[j] = to_bf16(guid[(size_t)(gg * 8 + j) * D_ + d]);
        Bp2[(size_t)gg * D_ + d] = v;
    }
}

// ---------------------------------------------------------------------------
// fused: per 16-row tile: diff+normalize -> gemm1 (MFMA) -> softmax ->
//        gemm2 (MFMA) -> blend write.  512 threads = 8 waves; LDS 52 KB.
// ---------------------------------------------------------------------------
__global__ __launch_bounds__(512, 4) void fused_kernel(const float* __restrict__ emb,
                                                       const short8* __restrict__ Bp1,
                                                       const short8* __restrict__ Bp2,
                                                       const float* __restrict__ rg2,
                                                       float* __restrict__ magw,
                                                       float* __restrict__ blend) {
    __shared__ short nrmh[MT][1032];   // bf16 normed; +16B pad: 2-way bank alias (free)
    __shared__ short wnA[MT][520];     // bf16 softmax weights (gemm2 A-frags)
    __shared__ float rg2s[G_];
    __shared__ float pred[MT][8];
    __shared__ float redmx[MT], redrs[MT];

    const int tid = threadIdx.x;
    const int wave = tid >> 6, lane = tid & 63;
    const int l15 = lane & 15, quad = lane >> 4;
    const int r0 = blockIdx.x * MT;

    rg2s[tid] = rg2[tid];   // 512 threads cover G_ exactly

    // ---- Phase 1: diffs + normalize (2 rows per wave) ----
#pragma unroll
    for (int i = 0; i < 2; ++i) {
        int rr = wave * 2 + i;
        int R = r0 + rr;
        if (R < R_) {
            int b = R / T_;
            int t = R - b * T_;
            const float4* p = (const float4*)(emb + ((size_t)b * S_ + t) * D_);
            float4 dv[4]; float ss = 0.f;
#pragma unroll
            for (int j = 0; j < 4; ++j) {
                float4 x0 = p[lane + 64 * j];
                float4 x1 = p[lane + 64 * j + 256];   // emb[b][t+1], contiguous
                dv[j] = make_float4(x1.x - x0.x, x1.y - x0.y, x1.z - x0.z, x1.w - x0.w);
                ss += dv[j].x * dv[j].x + dv[j].y * dv[j].y + dv[j].z * dv[j].z + dv[j].w * dv[j].w;
            }
#pragma unroll
            for (int m = 32; m >= 1; m >>= 1) ss += __shfl_xor(ss, m, 64);
            float mag = sqrtf(ss);
            float rmag = (mag > 1e-6f) ? (1.0f / mag) : 0.0f;
            if (lane == 0) magw[R] = tanhf(2.0f * mag);
#pragma unroll
            for (int j = 0; j < 4; ++j) {
                s16x4 h;
                h[0] = to_bf16(dv[j].x * rmag); h[1] = to_bf16(dv[j].y * rmag);
                h[2] = to_bf16(dv[j].z * rmag); h[3] = to_bf16(dv[j].w * rmag);
                *(s16x4*)&nrmh[rr][4 * lane + 256 * j] = h;
            }
        } else {
            s16x4 z = (s16x4)0;
#pragma unroll
            for (int j = 0; j < 4; ++j) *(s16x4*)&nrmh[rr][4 * lane + 256 * j] = z;
        }
    }
    __syncthreads();

    // ---- Phase 2: gemm1 — sims, wave owns g in [64w, 64w+64) ----
    f32x4 acc1[4];
#pragma unroll
    for (int nt = 0; nt < 4; ++nt) acc1[nt] = (f32x4)0.f;
    {
        const short8* Bb = Bp1 + (size_t)quad * G_ + wave * 64 + l15;
        short8 bc[4], bn[4];
#pragma unroll
        for (int nt = 0; nt < 4; ++nt) bc[nt] = Bb[nt * 16];
        for (int ks = 0; ks < 32; ++ks) {
            if (ks < 31) {
                const short8* Bnx = Bb + (size_t)(ks + 1) * 4 * G_;
#pragma unroll
                for (int nt = 0; nt < 4; ++nt) bn[nt] = Bnx[nt * 16];
            }
            short8 a = *(const short8*)&nrmh[l15][ks * 32 + quad * 8];
#pragma unroll
            for (int nt = 0; nt < 4; ++nt)
                acc1[nt] = __builtin_amdgcn_mfma_f32_16x16x32_bf16(a, bc[nt], acc1[nt], 0, 0, 0);
#pragma unroll
            for (int nt = 0; nt < 4; ++nt) bc[nt] = bn[nt];
        }
    }

    // ---- Phase 3: cross-wave softmax (logits in registers) ----
    {
        float pmax[4];
#pragma unroll
        for (int r2 = 0; r2 < 4; ++r2) pmax[r2] = -1e30f;
#pragma unroll
        for (int nt = 0; nt < 4; ++nt) {
            float rgv = rg2s[wave * 64 + nt * 16 + l15];
#pragma unroll
            for (int r2 = 0; r2 < 4; ++r2) {
                float lg = acc1[nt][r2] * rgv;
                acc1[nt][r2] = lg;
                pmax[r2] = fmaxf(pmax[r2], lg);
            }
        }
#pragma unroll
        for (int m = 8; m >= 1; m >>= 1) {
#pragma unroll
            for (int r2 = 0; r2 < 4; ++r2) pmax[r2] = fmaxf(pmax[r2], __shfl_xor(pmax[r2], m, 16));
        }
        if (l15 == 0) {
#pragma unroll
            for (int r2 = 0; r2 < 4; ++r2) pred[quad * 4 + r2][wave] = pmax[r2];
        }
        __syncthreads();
        if (tid < MT) {
            float m = pred[tid][0];
#pragma unroll
            for (int w2 = 1; w2 < 8; ++w2) m = fmaxf(m, pred[tid][w2]);
            redmx[tid] = m;
        }
        __syncthreads();
        float psum[4] = {0.f, 0.f, 0.f, 0.f};
#pragma unroll
        for (int nt = 0; nt < 4; ++nt) {
#pragma unroll
            for (int r2 = 0; r2 < 4; ++r2) {
                float e = __expf(acc1[nt][r2] - redmx[quad * 4 + r2]);
                acc1[nt][r2] = e;
                psum[r2] += e;
            }
        }
#pragma unroll
        for (int m = 8; m >= 1; m >>= 1) {
#pragma unroll
            for (int r2 = 0; r2 < 4; ++r2) psum[r2] += __shfl_xor(psum[r2], m, 16);
        }
        if (l15 == 0) {
#pragma unroll
            for (int r2 = 0; r2 < 4; ++r2) pred[quad * 4 + r2][wave] = psum[r2];
        }
        __syncthreads();
        if (tid < MT) {
            float s = 0.f;
#pragma unroll
            for (int w2 = 0; w2 < 8; ++w2) s += pred[tid][w2];
            redrs[tid] = 1.0f / s;
        }
        __syncthreads();
#pragma unroll
        for (int nt = 0; nt < 4; ++nt) {
#pragma unroll
            for (int r2 = 0; r2 < 4; ++r2) {
                float wv = acc1[nt][r2] * redrs[quad * 4 + r2];
                wnA[quad * 4 + r2][wave * 64 + nt * 16 + l15] = to_bf16(wv);
            }
        }
    }
    __syncthreads();

    // ---- Phase 4: gemm2 — influence, wave owns d in [128w, 128w+128) ----
    f32x4 acc2[8];
#pragma unroll
    for (int nt = 0; nt < 8; ++nt) acc2[nt] = (f32x4)0.f;
    {
        const short8* Bb = Bp2 + (size_t)quad * D_ + wave * 128 + l15;
        for (int ks = 0; ks < 16; ++ks) {
            short8 a = *(const short8*)&wnA[l15][ks * 32 + quad * 8];
            const short8* Bk = Bb + (size_t)ks * 4 * D_;
#pragma unroll
            for (int nt = 0; nt < 8; ++nt)
                acc2[nt] = __builtin_amdgcn_mfma_f32_16x16x32_bf16(a, Bk[nt * 16], acc2[nt], 0, 0, 0);
        }
    }

    // ---- Phase 5: blend = 0.6*normed + 0.4*infl ----
#pragma unroll
    for (int nt = 0; nt < 8; ++nt) {
        int d = wave * 128 + nt * 16 + l15;
#pragma unroll
        for (int r2 = 0; r2 < 4; ++r2) {
            int row = quad * 4 + r2;
            int R = r0 + row;
            if (R < R_) {
                float nv = from_bf16(nrmh[row][d]);
                blend[(size_t)R * D_ + d] = 0.6f * nv + 0.4f * acc2[nt][r2];
            }
        }
    }
}

// ---------------------------------------------------------------------------
// combine: register ring-buffer 8-tap window; block = 16 consecutive s, one b.
// ---------------------------------------------------------------------------
__global__ __launch_bounds__(256) void combine_kernel(const float* __restrict__ magw,
                                                      const float* __restrict__ blend,
                                                      float* __restrict__ out) {
    int blk = blockIdx.x;
    int b = blk >> 7;
    int s0 = (blk & 127) * 16;
    int tid = threadIdx.x;
    const float4* bl4 = (const float4*)blend;
    float4* out4 = (float4*)out;
    size_t rbase = (size_t)b * T_;
    float4 ring[8]; float mring[8];
#pragma unroll
    for (int a2 = 0; a2 < 8; ++a2) { ring[a2] = make_float4(0.f, 0.f, 0.f, 0.f); mring[a2] = 0.f; }
#pragma unroll
    for (int a2 = 0; a2 < 7; ++a2) {
        int t = s0 - 8 + a2;
        if (t >= 0) {
            ring[a2] = bl4[(rbase + t) * 256 + tid];
            mring[a2] = magw[rbase + t];
        }
    }
    if (s0 != 0) {
#pragma unroll
        for (int i = 0; i < 16; ++i) {
            int t = s0 + i - 1;
            ring[(i + 7) & 7] = bl4[(rbase + t) * 256 + tid];
            mring[(i + 7) & 7] = magw[rbase + t];
            float4 acc = make_float4(0.f, 0.f, 0.f, 0.f); float wsum = 0.f;
#pragma unroll
            for (int a = 1; a <= 8; ++a) {
                int slot = (i - a) & 7;
                float lin = 0.1f + (0.9f / 7.0f) * (float)(8 - a);
                float wt = lin * mring[slot];
                float4 v = ring[slot];
                acc.x += wt * v.x; acc.y += wt * v.y; acc.z += wt * v.z; acc.w += wt * v.w;
                wsum += wt;
            }
            float rws = 1.0f / fmaxf(wsum, 1e-8f);
            out4[((size_t)b * S_ + s0 + i) * 256 + tid] =
                make_float4(acc.x * rws, acc.y * rws, acc.z * rws, acc.w * rws);
        }
    } else {
#pragma unroll
        for (int i = 0; i < 16; ++i) {
            if (i >= 1) {
                int t = i - 1;
                ring[(i + 7) & 7] = bl4[(rbase + t) * 256 + tid];
                mring[(i + 7) & 7] = magw[rbase + t];
            }
            int w = (i < 8) ? i : 8;
            float rw = (w > 1) ? 0.9f / (float)(w - 1) : 0.0f;
            float4 acc = make_float4(0.f, 0.f, 0.f, 0.f); float wsum = 0.f;
            for (int a = 1; a <= w; ++a) {
                int slot = (i - a) & 7;
                float lin = 0.1f + rw * (float)(w - a);
                float wt = lin * mring[slot];
                float4 v = ring[slot];
                acc.x += wt * v.x; acc.y += wt * v.y; acc.z += wt * v.z; acc.w += wt * v.w;
                wsum += wt;
            }
            float rws = 1.0f / fmaxf(wsum, 1e-8f);
            out4[((size_t)b * S_ + i) * 256 + tid] =
                make_float4(acc.x * rws, acc.y * rws, acc.z * rws, acc.w * rws);
        }
    }
}

// ---------------------------------------------------------------------------
extern "C" void kernel_launch(void* const* d_in, const int* in_sizes, int n_in,
                              void* d_out, int out_size, void* d_ws, size_t ws_size,
                              hipStream_t stream) {
    const float* emb  = (const float*)d_in[0];
    const float* guid = (const float*)d_in[1];
    float* out = (float*)d_out;
    char* ws = (char*)d_ws;

    float*  rg2   = (float*)(ws + WSOFF_RG2);
    float*  magw  = (float*)(ws + WSOFF_MAGW);
    short8* Bp1   = (short8*)(ws + WSOFF_BP1);
    short8* Bp2   = (short8*)(ws + WSOFF_BP2);
    float*  blend = (float*)(ws + WSOFF_BL);

    prep1_kernel<<<G_, 64, 0, stream>>>(guid, rg2, Bp1);
    prep2_kernel<<<G_ / 8, 256, 0, stream>>>(guid, Bp2);
    fused_kernel<<<RPAD / MT, 512, 0, stream>>>(emb, Bp1, Bp2, rg2, magw, blend);
    combine_kernel<<<B_ * (S_ / 16), 256, 0, stream>>>(magw, blend, out);
}

// Round 4
// 128.281 us; speedup vs baseline: 3.5213x; 1.0994x over previous
//
#include <hip/hip_runtime.h>
#include <math.h>

// Dims fixed by reference setup_inputs
#define B_ 4
#define S_ 2048
#define D_ 1024
#define G_ 512
#define T_ 2047          // diff rows per batch
#define R_ 8188          // B_*T_ valid rows
#define RPAD 8192
#define MT 32            // diff rows per fused block
#define ABST 520         // AB LDS row stride (elems): 1040 B, 16-B aligned, 2-way bank alias

typedef __attribute__((ext_vector_type(8))) short short8;
typedef __attribute__((ext_vector_type(4))) short s16x4;
typedef __attribute__((ext_vector_type(4))) float f32x4;

// ws byte offsets
#define WSOFF_RG2  0u           // 512 f
#define WSOFF_MAGW 2048u        // 8192 f
#define WSOFF_BP1  34816u       // Bpack1 [128][512] short8 (1 MB)
#define WSOFF_BP2  1083392u     // Bpack2 [64][1024] short8 (1 MB)
#define WSOFF_NH   2131968u     // normh [8192][1024] bf16 (16 MB)
#define WSOFF_IH   18909184u    // inflh [8192][1024] bf16 (16 MB)

__device__ inline short to_bf16(float f) {
    union { float f; unsigned u; } v; v.f = f;
    unsigned r = v.u + 0x7fffu + ((v.u >> 16) & 1u);
    return (short)(r >> 16);
}
__device__ inline float fb(unsigned short h) {
    union { unsigned u; float f; } v;
    v.u = ((unsigned)h) << 16;
    return v.f;
}

// ---------------------------------------------------------------------------
// prep1: rg2[g] = 2/max(||guid[g]||,1e-8); Bpack1[k/8][g][k&7] = bf16(guid[g][k])
// ---------------------------------------------------------------------------
__global__ __launch_bounds__(64) void prep1_kernel(const float* __restrict__ guid,
                                                   float* __restrict__ rg2,
                                                   short8* __restrict__ Bp1) {
    int g = blockIdx.x, lane = threadIdx.x;
    const float4* gp = (const float4*)(guid + (size_t)g * D_);
    float ss = 0.f;
#pragma unroll
    for (int i = 0; i < 4; ++i) {
        float4 v = gp[lane + 64 * i];
        ss += v.x * v.x + v.y * v.y + v.z * v.z + v.w * v.w;
    }
#pragma unroll
    for (int m = 32; m >= 1; m >>= 1) ss += __shfl_xor(ss, m, 64);
    if (lane == 0) rg2[g] = 2.0f / fmaxf(sqrtf(ss), 1e-8f);
#pragma unroll
    for (int h = 0; h < 2; ++h) {
        int kg = lane + 64 * h;
        const float* src = guid + (size_t)g * D_ + kg * 8;
        short8 v;
#pragma unroll
        for (int j = 0; j < 8; ++j) v[j] = to_bf16(src[j]);
        Bp1[(size_t)kg * G_ + g] = v;
    }
}

// ---------------------------------------------------------------------------
// prep2: Bpack2[g/8][d][g&7] = bf16(guid[g][d])
// ---------------------------------------------------------------------------
__global__ __launch_bounds__(256) void prep2_kernel(const float* __restrict__ guid,
                                                    short8* __restrict__ Bp2) {
    int gg = blockIdx.x, tid = threadIdx.x;
#pragma unroll
    for (int dd = 0; dd < 4; ++dd) {
        int d = tid + 256 * dd;
        short8 v;
#pragma unroll
        for (int j = 0; j < 8; ++j) v[j] = to_bf16(guid[(size_t)(gg * 8 + j) * D_ + d]);
        Bp2[(size_t)gg * D_ + d] = v;
    }
}

// ---------------------------------------------------------------------------
// fused: 32-row tile, 16 waves. diff/norm -> gemm1 (2 k-passes, A staged in
// union LDS buffer) -> softmax -> gemm2 -> inflh/normh bf16 out.
// ---------------------------------------------------------------------------
__global__ __launch_bounds__(1024, 4) void fused_kernel(const float* __restrict__ emb,
                                                        const short8* __restrict__ Bp1,
                                                        const short8* __restrict__ Bp2,
                                                        const float* __restrict__ rg2,
                                                        float* __restrict__ magw,
                                                        short* __restrict__ normh,
                                                        short* __restrict__ inflh) {
    __shared__ short AB[MT][ABST];      // normed halves, then softmax weights
    __shared__ float rg2s[G_];
    __shared__ float pred[MT][16];
    __shared__ float redmx[MT], redrs[MT];

    const int tid = threadIdx.x;
    const int wave = tid >> 6, lane = tid & 63;
    const int l15 = lane & 15, quad = lane >> 4;
    const int r0 = blockIdx.x * MT;

    if (tid < G_) rg2s[tid] = rg2[tid];

    // ---- Phase 1: diff + normalize, 2 rows/wave; stage k<512 half in LDS,
    //      hold k>=512 half in regs; write normh bf16 to global ----
    s16x4 hold[2][2];
#pragma unroll
    for (int i = 0; i < 2; ++i) {
        int rr = wave * 2 + i;
        int R = r0 + rr;
        if (R < R_) {
            int b = R / T_;
            int t = R - b * T_;
            const float4* p = (const float4*)(emb + ((size_t)b * S_ + t) * D_);
            float4 dv[4]; float ss = 0.f;
#pragma unroll
            for (int j = 0; j < 4; ++j) {
                float4 x0 = p[lane + 64 * j];
                float4 x1 = p[lane + 64 * j + 256];
                dv[j] = make_float4(x1.x - x0.x, x1.y - x0.y, x1.z - x0.z, x1.w - x0.w);
                ss += dv[j].x * dv[j].x + dv[j].y * dv[j].y + dv[j].z * dv[j].z + dv[j].w * dv[j].w;
            }
#pragma unroll
            for (int m = 32; m >= 1; m >>= 1) ss += __shfl_xor(ss, m, 64);
            float mag = sqrtf(ss);
            float rmag = (mag > 1e-6f) ? (1.0f / mag) : 0.0f;
            if (lane == 0) magw[R] = tanhf(2.0f * mag);
            s16x4 h[4];
#pragma unroll
            for (int j = 0; j < 4; ++j) {
                h[j][0] = to_bf16(dv[j].x * rmag); h[j][1] = to_bf16(dv[j].y * rmag);
                h[j][2] = to_bf16(dv[j].z * rmag); h[j][3] = to_bf16(dv[j].w * rmag);
            }
            short* nb = normh + (size_t)R * D_ + 4 * lane;
#pragma unroll
            for (int j = 0; j < 4; ++j) *(s16x4*)(nb + 256 * j) = h[j];
            *(s16x4*)&AB[rr][4 * lane] = h[0];
            *(s16x4*)&AB[rr][4 * lane + 256] = h[1];
            hold[i][0] = h[2]; hold[i][1] = h[3];
        } else {
            s16x4 z = (s16x4)0;
            *(s16x4*)&AB[rr][4 * lane] = z;
            *(s16x4*)&AB[rr][4 * lane + 256] = z;
            hold[i][0] = z; hold[i][1] = z;
        }
    }
    __syncthreads();

    // ---- Phase 2: gemm1 (two 512-k passes). wave owns g in [32w, 32w+32) ----
    f32x4 acc1[2][2];
#pragma unroll
    for (int mt = 0; mt < 2; ++mt)
#pragma unroll
        for (int nt = 0; nt < 2; ++nt) acc1[mt][nt] = (f32x4)0.f;
#pragma unroll
    for (int p = 0; p < 2; ++p) {
        if (p == 1) {
            __syncthreads();
#pragma unroll
            for (int i = 0; i < 2; ++i) {
                int rr = wave * 2 + i;
                *(s16x4*)&AB[rr][4 * lane] = hold[i][0];
                *(s16x4*)&AB[rr][4 * lane + 256] = hold[i][1];
            }
            __syncthreads();
        }
        const short8* Bb = Bp1 + ((size_t)(64 * p + quad)) * G_ + wave * 32 + l15;
        short8 bc0 = Bb[0], bc1 = Bb[16], bn0, bn1;
        for (int ks = 0; ks < 16; ++ks) {
            if (ks < 15) {
                const short8* Bx = Bb + (size_t)(ks + 1) * 4 * G_;
                bn0 = Bx[0]; bn1 = Bx[16];
            }
            short8 a0 = *(const short8*)&AB[l15][ks * 32 + quad * 8];
            short8 a1 = *(const short8*)&AB[16 + l15][ks * 32 + quad * 8];
            acc1[0][0] = __builtin_amdgcn_mfma_f32_16x16x32_bf16(a0, bc0, acc1[0][0], 0, 0, 0);
            acc1[0][1] = __builtin_amdgcn_mfma_f32_16x16x32_bf16(a0, bc1, acc1[0][1], 0, 0, 0);
            acc1[1][0] = __builtin_amdgcn_mfma_f32_16x16x32_bf16(a1, bc0, acc1[1][0], 0, 0, 0);
            acc1[1][1] = __builtin_amdgcn_mfma_f32_16x16x32_bf16(a1, bc1, acc1[1][1], 0, 0, 0);
            bc0 = bn0; bc1 = bn1;
        }
    }

    // ---- Phase 3: cross-wave softmax; weights -> AB (gemm2 A-frags) ----
    {
        float pmax[2][4];
#pragma unroll
        for (int mt = 0; mt < 2; ++mt)
#pragma unroll
            for (int r2 = 0; r2 < 4; ++r2) pmax[mt][r2] = -1e30f;
#pragma unroll
        for (int mt = 0; mt < 2; ++mt)
#pragma unroll
            for (int nt = 0; nt < 2; ++nt) {
                float rgv = rg2s[wave * 32 + nt * 16 + l15];
#pragma unroll
                for (int r2 = 0; r2 < 4; ++r2) {
                    float lg = acc1[mt][nt][r2] * rgv;
                    acc1[mt][nt][r2] = lg;
                    pmax[mt][r2] = fmaxf(pmax[mt][r2], lg);
                }
            }
#pragma unroll
        for (int m = 8; m >= 1; m >>= 1)
#pragma unroll
            for (int mt = 0; mt < 2; ++mt)
#pragma unroll
                for (int r2 = 0; r2 < 4; ++r2)
                    pmax[mt][r2] = fmaxf(pmax[mt][r2], __shfl_xor(pmax[mt][r2], m, 16));
        if (l15 == 0) {
#pragma unroll
            for (int mt = 0; mt < 2; ++mt)
#pragma unroll
                for (int r2 = 0; r2 < 4; ++r2)
                    pred[mt * 16 + quad * 4 + r2][wave] = pmax[mt][r2];
        }
        __syncthreads();
        if (tid < MT) {
            float m = pred[tid][0];
#pragma unroll
            for (int w2 = 1; w2 < 16; ++w2) m = fmaxf(m, pred[tid][w2]);
            redmx[tid] = m;
        }
        __syncthreads();
        float psum[2][4];
#pragma unroll
        for (int mt = 0; mt < 2; ++mt)
#pragma unroll
            for (int r2 = 0; r2 < 4; ++r2) psum[mt][r2] = 0.f;
#pragma unroll
        for (int mt = 0; mt < 2; ++mt)
#pragma unroll
            for (int nt = 0; nt < 2; ++nt)
#pragma unroll
                for (int r2 = 0; r2 < 4; ++r2) {
                    float e = __expf(acc1[mt][nt][r2] - redmx[mt * 16 + quad * 4 + r2]);
                    acc1[mt][nt][r2] = e;
                    psum[mt][r2] += e;
                }
#pragma unroll
        for (int m = 8; m >= 1; m >>= 1)
#pragma unroll
            for (int mt = 0; mt < 2; ++mt)
#pragma unroll
                for (int r2 = 0; r2 < 4; ++r2)
                    psum[mt][r2] += __shfl_xor(psum[mt][r2], m, 16);
        if (l15 == 0) {
#pragma unroll
            for (int mt = 0; mt < 2; ++mt)
#pragma unroll
                for (int r2 = 0; r2 < 4; ++r2)
                    pred[mt * 16 + quad * 4 + r2][wave] = psum[mt][r2];
        }
        __syncthreads();
        if (tid < MT) {
            float s = 0.f;
#pragma unroll
            for (int w2 = 0; w2 < 16; ++w2) s += pred[tid][w2];
            redrs[tid] = 1.0f / s;
        }
        __syncthreads();
#pragma unroll
        for (int mt = 0; mt < 2; ++mt)
#pragma unroll
            for (int nt = 0; nt < 2; ++nt)
#pragma unroll
                for (int r2 = 0; r2 < 4; ++r2) {
                    int row = mt * 16 + quad * 4 + r2;
                    AB[row][wave * 32 + nt * 16 + l15] =
                        to_bf16(acc1[mt][nt][r2] * redrs[row]);
                }
    }
    __syncthreads();

    // ---- Phase 4: gemm2. wave owns d in [64w, 64w+64) ----
    f32x4 acc2[2][4];
#pragma unroll
    for (int mt = 0; mt < 2; ++mt)
#pragma unroll
        for (int nt = 0; nt < 4; ++nt) acc2[mt][nt] = (f32x4)0.f;
    {
        const short8* Bb = Bp2 + (size_t)quad * D_ + wave * 64 + l15;
        short8 bc[4], bn[4];
#pragma unroll
        for (int nt = 0; nt < 4; ++nt) bc[nt] = Bb[nt * 16];
        for (int ks = 0; ks < 16; ++ks) {
            if (ks < 15) {
                const short8* Bx = Bb + (size_t)(ks + 1) * 4 * D_;
#pragma unroll
                for (int nt = 0; nt < 4; ++nt) bn[nt] = Bx[nt * 16];
            }
            short8 a0 = *(const short8*)&AB[l15][ks * 32 + quad * 8];
            short8 a1 = *(const short8*)&AB[16 + l15][ks * 32 + quad * 8];
#pragma unroll
            for (int nt = 0; nt < 4; ++nt) {
                acc2[0][nt] = __builtin_amdgcn_mfma_f32_16x16x32_bf16(a0, bc[nt], acc2[0][nt], 0, 0, 0);
                acc2[1][nt] = __builtin_amdgcn_mfma_f32_16x16x32_bf16(a1, bc[nt], acc2[1][nt], 0, 0, 0);
            }
#pragma unroll
            for (int nt = 0; nt < 4; ++nt) bc[nt] = bn[nt];
        }
    }

    // ---- Phase 5: influence bf16 out ----
#pragma unroll
    for (int mt = 0; mt < 2; ++mt)
#pragma unroll
        for (int nt = 0; nt < 4; ++nt) {
            int d = wave * 64 + nt * 16 + l15;
#pragma unroll
            for (int r2 = 0; r2 < 4; ++r2) {
                int R = r0 + mt * 16 + quad * 4 + r2;
                if (R < R_) inflh[(size_t)R * D_ + d] = to_bf16(acc2[mt][nt][r2]);
            }
        }
}

// ---------------------------------------------------------------------------
// combine: 8-tap ring over bf16 normh/inflh; block = 16 s x 512-d half.
// grid 1024 = B_ * 128 * 2
// ---------------------------------------------------------------------------
__global__ __launch_bounds__(256) void combine_kernel(const float* __restrict__ magw,
                                                      const unsigned short* __restrict__ normh,
                                                      const unsigned short* __restrict__ inflh,
                                                      float* __restrict__ out) {
    int blk = blockIdx.x;
    int b = blk >> 8;
    int rem = blk & 255;
    int s0 = (rem >> 1) * 16;
    int d = (rem & 1) * 512 + threadIdx.x * 2;
    size_t rbase = (size_t)b * T_;

    float2 ring[8]; float mring[8];
#pragma unroll
    for (int a2 = 0; a2 < 8; ++a2) { ring[a2] = make_float2(0.f, 0.f); mring[a2] = 0.f; }

#define LOADBL(t_, dst_)                                                        \
    {                                                                           \
        size_t off_ = (rbase + (t_)) * D_ + d;                                  \
        ushort2 n2_ = *(const ushort2*)(normh + off_);                          \
        ushort2 i2_ = *(const ushort2*)(inflh + off_);                          \
        dst_ = make_float2(0.6f * fb(n2_.x) + 0.4f * fb(i2_.x),                 \
                           0.6f * fb(n2_.y) + 0.4f * fb(i2_.y));                \
    }

#pragma unroll
    for (int a2 = 0; a2 < 7; ++a2) {
        int t = s0 - 8 + a2;
        if (t >= 0) {
            LOADBL(t, ring[a2]);
            mring[a2] = magw[rbase + t];
        }
    }
    if (s0 != 0) {
#pragma unroll
        for (int i = 0; i < 16; ++i) {
            int t = s0 + i - 1;
            LOADBL(t, ring[(i + 7) & 7]);
            mring[(i + 7) & 7] = magw[rbase + t];
            float2 acc = make_float2(0.f, 0.f); float wsum = 0.f;
#pragma unroll
            for (int a = 1; a <= 8; ++a) {
                int slot = (i - a) & 7;
                float lin = 0.1f + (0.9f / 7.0f) * (float)(8 - a);
                float wt = lin * mring[slot];
                acc.x += wt * ring[slot].x; acc.y += wt * ring[slot].y;
                wsum += wt;
            }
            float rws = 1.0f / fmaxf(wsum, 1e-8f);
            *(float2*)&out[((size_t)b * S_ + s0 + i) * D_ + d] =
                make_float2(acc.x * rws, acc.y * rws);
        }
    } else {
#pragma unroll
        for (int i = 0; i < 16; ++i) {
            if (i >= 1) {
                int t = i - 1;
                LOADBL(t, ring[(i + 7) & 7]);
                mring[(i + 7) & 7] = magw[rbase + t];
            }
            int w = (i < 8) ? i : 8;
            float rw = (w > 1) ? 0.9f / (float)(w - 1) : 0.0f;
            float2 acc = make_float2(0.f, 0.f); float wsum = 0.f;
            for (int a = 1; a <= w; ++a) {
                int slot = (i - a) & 7;
                float lin = 0.1f + rw * (float)(w - a);
                float wt = lin * mring[slot];
                acc.x += wt * ring[slot].x; acc.y += wt * ring[slot].y;
                wsum += wt;
            }
            float rws = 1.0f / fmaxf(wsum, 1e-8f);
            *(float2*)&out[((size_t)b * S_ + i) * D_ + d] =
                make_float2(acc.x * rws, acc.y * rws);
        }
    }
#undef LOADBL
}

// ---------------------------------------------------------------------------
extern "C" void kernel_launch(void* const* d_in, const int* in_sizes, int n_in,
                              void* d_out, int out_size, void* d_ws, size_t ws_size,
                              hipStream_t stream) {
    const float* emb  = (const float*)d_in[0];
    const float* guid = (const float*)d_in[1];
    float* out = (float*)d_out;
    char* ws = (char*)d_ws;

    float*  rg2   = (float*)(ws + WSOFF_RG2);
    float*  magw  = (float*)(ws + WSOFF_MAGW);
    short8* Bp1   = (short8*)(ws + WSOFF_BP1);
    short8* Bp2   = (short8*)(ws + WSOFF_BP2);
    short*  normh = (short*)(ws + WSOFF_NH);
    short*  inflh = (short*)(ws + WSOFF_IH);

    prep1_kernel<<<G_, 64, 0, stream>>>(guid, rg2, Bp1);
    prep2_kernel<<<G_ / 8, 256, 0, stream>>>(guid, Bp2);
    fused_kernel<<<RPAD / MT, 1024, 0, stream>>>(emb, Bp1, Bp2, rg2, magw, normh, inflh);
    combine_kernel<<<B_ * 128 * 2, 256, 0, stream>>>(magw, (const unsigned short*)normh,
                                                     (const unsigned short*)inflh, out);
}